// Round 11
// baseline (353.216 us; speedup 1.0000x reference)
//
#include <hip/hip_runtime.h>

#define NN   100000
#define EMB  64
#define HID  128
#define OUTD 64
#define NE   1600000
#define NL   200000
#define NBUK 6250     // NN/16 buckets of exactly 16 nodes
#define NG   8        // per-XCD privatized copies
#define CAPG 88       // per-XCD bucket capacity; E=32, ~10 sigma margin
#define BSTR 6272     // padded per-group bcnt stride
#define XS   130      // padded LDS row stride (words) -> staging stores max 2-way conflict

__device__ __forceinline__ unsigned xcc_id() {
    unsigned v;
    asm volatile("s_getreg_b32 %0, hwreg(HW_REG_XCC_ID)" : "=s"(v));
    return v & (NG - 1);
}

// ---------------- bucket edges by dst>>4 into per-XCD private buckets ----------------
__global__ void bucket16_kernel(const int* __restrict__ src, const int* __restrict__ dst,
                                int* __restrict__ bcnt, int* __restrict__ tmp) {
    int i = blockIdx.x * blockDim.x + threadIdx.x;
    if (i >= NE) return;
    unsigned g = xcc_id();          // wave-uniform physical XCD id
    int d = dst[i];
    int s = src[i];
    int b = d >> 4;
    int pos = atomicAdd(&bcnt[g * BSTR + b], 1);
    if (pos < CAPG) tmp[(g * NBUK + b) * CAPG + pos] = ((d & 15) << 17) | s;
}

// ---------------- per-bucket aggregation via LDS micro-CSR + register gather -------
// L1=true : out[i] = (1/max(deg,1)) * sum_{j in N(i)} x[j]
// L1=false: out[i] = (1/max(deg,1)) * sum x[j] + hz[i] + bias   (fused z)
template<bool L1>
__global__ void __launch_bounds__(256) agg16_kernel(
        const int* __restrict__ bcnt, const int* __restrict__ tmp,
        const float* __restrict__ x,
        const float* __restrict__ hz, const float* __restrict__ bias,
        float* __restrict__ outp) {
    __shared__ int scnt[16];
    __shared__ int soff[16];
    __shared__ int scur[16];
    __shared__ int slist[NG * CAPG];   // <= 704 entries

    const int b    = blockIdx.x;
    const int tid  = threadIdx.x;
    const int lane = tid & 63;
    const int wv   = tid >> 6;         // 0..3

    if (tid < 16) scnt[tid] = 0;
    __syncthreads();

    // phase 1: per-node counts (= degree) over the 8 private lists
#pragma unroll
    for (int g = 0; g < NG; ++g) {
        const int cg = min(bcnt[g * BSTR + b], CAPG);
        const int* tb = tmp + (size_t)(g * NBUK + b) * CAPG;
        for (int i = tid; i < cg; i += 256)
            atomicAdd(&scnt[tb[i] >> 17], 1);
    }
    __syncthreads();

    // phase 2: exclusive scan of 16
    if (tid == 0) {
        int acc = 0;
        for (int r = 0; r < 16; ++r) {
            soff[r] = acc;
            scur[r] = acc;
            acc += scnt[r];
        }
    }
    __syncthreads();

    // phase 3: scatter src ids into per-node lists
#pragma unroll
    for (int g = 0; g < NG; ++g) {
        const int cg = min(bcnt[g * BSTR + b], CAPG);
        const int* tb = tmp + (size_t)(g * NBUK + b) * CAPG;
        for (int i = tid; i < cg; i += 256) {
            int p = tb[i];
            int pos = atomicAdd(&scur[p >> 17], 1);
            slist[pos] = p & 0x1FFFF;
        }
    }
    __syncthreads();

    // phase 4: per-node register gather; wave wv owns nodes wv, wv+4, wv+8, wv+12
    for (int r = wv; r < 16; r += 4) {
        const int node = b * 16 + r;
        const int s = soff[r];
        const int d = scnt[r];
        float acc = 0.f;
        int j = 0;
        for (; j + 8 <= d; j += 8) {
            int c0 = slist[s + j + 0], c1 = slist[s + j + 1];
            int c2 = slist[s + j + 2], c3 = slist[s + j + 3];
            int c4 = slist[s + j + 4], c5 = slist[s + j + 5];
            int c6 = slist[s + j + 6], c7 = slist[s + j + 7];
            float v0 = x[(size_t)c0 * 64 + lane];
            float v1 = x[(size_t)c1 * 64 + lane];
            float v2 = x[(size_t)c2 * 64 + lane];
            float v3 = x[(size_t)c3 * 64 + lane];
            float v4 = x[(size_t)c4 * 64 + lane];
            float v5 = x[(size_t)c5 * 64 + lane];
            float v6 = x[(size_t)c6 * 64 + lane];
            float v7 = x[(size_t)c7 * 64 + lane];
            acc += ((v0 + v1) + (v2 + v3)) + ((v4 + v5) + (v6 + v7));
        }
        if (j + 4 <= d) {
            int c0 = slist[s + j + 0], c1 = slist[s + j + 1];
            int c2 = slist[s + j + 2], c3 = slist[s + j + 3];
            float v0 = x[(size_t)c0 * 64 + lane];
            float v1 = x[(size_t)c1 * 64 + lane];
            float v2 = x[(size_t)c2 * 64 + lane];
            float v3 = x[(size_t)c3 * 64 + lane];
            acc += (v0 + v1) + (v2 + v3);
            j += 4;
        }
        for (; j < d; ++j) acc += x[(size_t)slist[s + j] * 64 + lane];

        const float inv = 1.0f / fmaxf((float)d, 1.0f);
        if (L1) {
            outp[(size_t)node * 64 + lane] = acc * inv;
        } else {
            outp[(size_t)node * 64 + lane] =
                acc * inv + hz[(size_t)node * 64 + lane] + bias[lane];
        }
    }
}

// ---------------- tiled GEMM: 128 nodes x 128 outs per block, K=128 blocked by 64 ----
// MODE 1 (layer 1): X = cat(agg, emb), W = cat_c(w1l, w1r), out = relu(XW^T + b1)
// MODE 2 (layer 2): X = h, W rows: o<64 w2l[o], o>=64 w2r[o-64]; outs->outA(p2)/outB(hz)
template<int MODE>
__global__ void __launch_bounds__(512, 1) gemm_kernel(
        const float* __restrict__ Xa, const float* __restrict__ Xb,
        const float* __restrict__ Wa, const float* __restrict__ Wb,
        const float* __restrict__ bias,
        float* __restrict__ outA, float* __restrict__ outB) {
    __shared__ float lds_x[64 * XS];  // [c_local][node_local], padded stride
    __shared__ float lds_w[64 * XS];  // [c_local][o], padded stride

    const int tid = threadIdx.x;
    const int n_base = blockIdx.x * 128;

    const int ng = tid & 31;   // nodes 4*ng .. 4*ng+3
    const int og = tid >> 5;   // outs  8*og .. 8*og+7
    const int o0 = og * 8;

    float acc[4][8];
#pragma unroll
    for (int i = 0; i < 4; ++i)
#pragma unroll
        for (int j = 0; j < 8; ++j) acc[i][j] = 0.f;

#pragma unroll
    for (int half = 0; half < 2; ++half) {
        // ---- stage W half (transposed): lds_w[c][o] ----
        {
            int o = tid >> 2;
            int wslot = tid & 3;
#pragma unroll
            for (int k = 0; k < 4; ++k) {
                int s = wslot + 4 * k;   // float4 slot 0..15 within 64 c's
                int c4 = s * 4;          // local c
                float4 v;
                if (MODE == 1) {
                    v = (half == 0) ? ((const float4*)Wa)[o * 16 + s]
                                    : ((const float4*)Wb)[o * 16 + s];
                } else {
                    int cg4 = half * 16 + s;
                    v = (o < 64) ? ((const float4*)Wa)[o * 32 + cg4]
                                 : ((const float4*)Wb)[(o - 64) * 32 + cg4];
                }
                lds_w[(c4 + 0) * XS + o] = v.x;
                lds_w[(c4 + 1) * XS + o] = v.y;
                lds_w[(c4 + 2) * XS + o] = v.z;
                lds_w[(c4 + 3) * XS + o] = v.w;
            }
        }
        // ---- stage X half (transposed): lds_x[c][n_local] ----
        {
            int nl = tid >> 2;
            int cslot = tid & 3;
            int n = n_base + nl;
            bool ok = n < NN;
#pragma unroll
            for (int k = 0; k < 4; ++k) {
                int s = cslot + 4 * k;   // 0..15
                int c4 = s * 4;
                float4 v = make_float4(0.f, 0.f, 0.f, 0.f);
                if (ok) {
                    if (MODE == 1) {
                        v = (half == 0) ? ((const float4*)Xa)[(size_t)n * 16 + s]
                                        : ((const float4*)Xb)[(size_t)n * 16 + s];
                    } else {
                        v = ((const float4*)Xa)[(size_t)n * 32 + half * 16 + s];
                    }
                }
                lds_x[(c4 + 0) * XS + nl] = v.x;
                lds_x[(c4 + 1) * XS + nl] = v.y;
                lds_x[(c4 + 2) * XS + nl] = v.z;
                lds_x[(c4 + 3) * XS + nl] = v.w;
            }
        }
        __syncthreads();

        // ---- compute half ----
#pragma unroll 2
        for (int c = 0; c < 64; ++c) {
            float4 xv = *(const float4*)&lds_x[c * XS + ng * 4];
            float4 w0 = *(const float4*)&lds_w[c * XS + o0];
            float4 w1 = *(const float4*)&lds_w[c * XS + o0 + 4];
            float xr[4] = {xv.x, xv.y, xv.z, xv.w};
            float wr[8] = {w0.x, w0.y, w0.z, w0.w, w1.x, w1.y, w1.z, w1.w};
#pragma unroll
            for (int i = 0; i < 4; ++i)
#pragma unroll
                for (int j = 0; j < 8; ++j) acc[i][j] += xr[i] * wr[j];
        }
        __syncthreads();
    }

    // ---- epilogue ----
    if (MODE == 1) {
        float bj[8];
#pragma unroll
        for (int j = 0; j < 8; ++j) bj[j] = bias[o0 + j];
#pragma unroll
        for (int i = 0; i < 4; ++i) {
            int n = n_base + ng * 4 + i;
            if (n >= NN) continue;
            float4 lo = make_float4(fmaxf(acc[i][0] + bj[0], 0.f), fmaxf(acc[i][1] + bj[1], 0.f),
                                    fmaxf(acc[i][2] + bj[2], 0.f), fmaxf(acc[i][3] + bj[3], 0.f));
            float4 hi = make_float4(fmaxf(acc[i][4] + bj[4], 0.f), fmaxf(acc[i][5] + bj[5], 0.f),
                                    fmaxf(acc[i][6] + bj[6], 0.f), fmaxf(acc[i][7] + bj[7], 0.f));
            ((float4*)outA)[(size_t)n * 32 + (o0 >> 2)] = lo;
            ((float4*)outA)[(size_t)n * 32 + (o0 >> 2) + 1] = hi;
        }
    } else {
        float* dstp = (og < 8) ? outA : outB;
        int ob = (og < 8) ? o0 : (o0 - 64);
#pragma unroll
        for (int i = 0; i < 4; ++i) {
            int n = n_base + ng * 4 + i;
            if (n >= NN) continue;
            float4 lo = make_float4(acc[i][0], acc[i][1], acc[i][2], acc[i][3]);
            float4 hi = make_float4(acc[i][4], acc[i][5], acc[i][6], acc[i][7]);
            ((float4*)dstp)[(size_t)n * 16 + (ob >> 2)] = lo;
            ((float4*)dstp)[(size_t)n * 16 + (ob >> 2) + 1] = hi;
        }
    }
}

// ---------------- decode: out[k] = dot(z[a[k]], z[b[k]]) ----------------
__global__ void decode_kernel(const int* __restrict__ a, const int* __restrict__ b,
                              const float* __restrict__ z, float* __restrict__ out) {
    int t = blockIdx.x * blockDim.x + threadIdx.x;
    int k = t >> 4;
    int q = t & 15;
    if (k >= NL) return;
    int ia = a[k], ib = b[k];
    float4 va = ((const float4*)z)[ia * 16 + q];
    float4 vb = ((const float4*)z)[ib * 16 + q];
    float s = va.x * vb.x + va.y * vb.y + va.z * vb.z + va.w * vb.w;
    s += __shfl_xor(s, 1, 64);
    s += __shfl_xor(s, 2, 64);
    s += __shfl_xor(s, 4, 64);
    s += __shfl_xor(s, 8, 64);
    if (q == 0) out[k] = s;
}

extern "C" void kernel_launch(void* const* d_in, const int* in_sizes, int n_in,
                              void* d_out, int out_size, void* d_ws, size_t ws_size,
                              hipStream_t stream) {
    const float* emb = (const float*)d_in[0];
    const float* w1l = (const float*)d_in[1];
    const float* w1r = (const float*)d_in[2];
    const float* b1  = (const float*)d_in[3];
    const float* w2l = (const float*)d_in[4];
    const float* w2r = (const float*)d_in[5];
    const float* b2  = (const float*)d_in[6];
    const int*   ei  = (const int*)d_in[7];
    const int*   eli = (const int*)d_in[8];
    float* out = (float*)d_out;

    // workspace layout (~120 MB)
    int* bcnt    = (int*)d_ws;                                // NG*BSTR = 50,176
    int* tmp     = bcnt + NG * BSTR;                          // NG*NBUK*CAPG = 4,400,000
    float* agg   = (float*)(tmp + (size_t)NG * NBUK * CAPG);  // NN*64 (reused as hz)
    float* h     = agg + (size_t)NN * 64;                     // NN*128 (reused as z)
    float* p2    = h + (size_t)NN * 128;                      // NN*64
    float* hz    = agg;
    float* z     = h;

    const int* src = ei;
    const int* dst = ei + NE;

    hipMemsetAsync(bcnt, 0, (size_t)NG * BSTR * sizeof(int), stream);

    // bucket edges by dst>>4 into per-XCD private lists
    bucket16_kernel<<<(NE + 255) / 256, 256, 0, stream>>>(src, dst, bcnt, tmp);

    const int NT = (NN + 127) / 128;  // 782 tiles

    // layer 1: agg = mean-gather(emb); h = relu(cat(agg,emb) @ cat(w1l,w1r)^T + b1)
    agg16_kernel<true><<<NBUK, 256, 0, stream>>>(bcnt, tmp, emb, nullptr, nullptr, agg);
    gemm_kernel<1><<<NT, 512, 0, stream>>>(agg, emb, w1l, w1r, b1, h, nullptr);

    // layer 2: {p2, hz} = h @ {w2l, w2r}^T ; z = mean-gather(p2) + hz + b2
    gemm_kernel<2><<<NT, 512, 0, stream>>>(h, nullptr, w2l, w2r, nullptr, p2, hz);
    agg16_kernel<false><<<NBUK, 256, 0, stream>>>(bcnt, tmp, p2, hz, b2, z);

    // decode
    decode_kernel<<<(NL * 16 + 255) / 256, 256, 0, stream>>>(eli, eli + NL, z, out);
}

// Round 12
// 328.372 us; speedup vs baseline: 1.0757x; 1.0757x over previous
//
#include <hip/hip_runtime.h>

#define NN   100000
#define EMB  64
#define HID  128
#define OUTD 64
#define NE   1600000
#define NL   200000
#define NBUK 6250     // NN/16 buckets of exactly 16 nodes
#define NG   8        // per-XCD privatized copies
#define CAPG 128      // per-XCD bucket capacity (pow2 for shift/mask); E=32
#define BSTR 6272     // padded per-group bcnt stride
#define XS   130      // padded LDS row stride (words)

__device__ __forceinline__ unsigned xcc_id() {
    unsigned v;
    asm volatile("s_getreg_b32 %0, hwreg(HW_REG_XCC_ID)" : "=s"(v));
    return v & (NG - 1);
}

// ---------------- bucket edges by dst>>4 into per-XCD private buckets ----------------
__global__ void bucket16_kernel(const int* __restrict__ src, const int* __restrict__ dst,
                                int* __restrict__ bcnt, int* __restrict__ tmp) {
    int i = blockIdx.x * blockDim.x + threadIdx.x;
    if (i >= NE) return;
    unsigned g = xcc_id();          // wave-uniform physical XCD id
    int d = dst[i];
    int s = src[i];
    int b = d >> 4;
    int pos = atomicAdd(&bcnt[g * BSTR + b], 1);
    if (pos < CAPG) tmp[((size_t)g * NBUK + b) * CAPG + pos] = ((d & 15) << 17) | s;
}

// ---------------- per-bucket aggregation: flatten lists -> micro-CSR -> reg gather ----
// L1=true : out[i] = (1/max(deg,1)) * sum_{j in N(i)} x[j]
// L1=false: out[i] = (1/max(deg,1)) * sum x[j] + hz[i] + bias   (fused z)
template<bool L1>
__global__ void __launch_bounds__(256) agg16_kernel(
        const int* __restrict__ bcnt, const int* __restrict__ tmp,
        const float* __restrict__ x,
        const float* __restrict__ hz, const float* __restrict__ bias,
        float* __restrict__ outp) {
    __shared__ int cgs[NG];
    __shared__ int goff[NG];
    __shared__ int total;
    __shared__ int scnt[16];
    __shared__ int soff[16];
    __shared__ int scur[16];
    __shared__ int plist[NG * CAPG];   // flattened packed entries (dense)
    __shared__ int slist[NG * CAPG];   // grouped-by-node src ids

    const int b    = blockIdx.x;
    const int tid  = threadIdx.x;
    const int lane = tid & 63;
    const int wv   = tid >> 6;         // 0..3

    if (tid < NG) cgs[tid] = min(bcnt[tid * BSTR + b], CAPG);
    if (tid < 16) scnt[tid] = 0;
    __syncthreads();

    if (tid == 0) {
        int acc = 0;
#pragma unroll
        for (int g = 0; g < NG; ++g) { int c = cgs[g]; goff[g] = acc; acc += c; }
        total = acc;
    }
    __syncthreads();

    // flatten: one dense coalesced read of all 8 sub-lists into plist
    for (int t = tid; t < NG * CAPG; t += 256) {
        int g = t >> 7;          // CAPG = 128
        int i = t & (CAPG - 1);
        if (i < cgs[g])
            plist[goff[g] + i] = tmp[((size_t)g * NBUK + b) * CAPG + i];
    }
    __syncthreads();

    const int cnt = total;

    // phase 1: per-node counts (= degree), dense from LDS
    for (int i = tid; i < cnt; i += 256)
        atomicAdd(&scnt[plist[i] >> 17], 1);
    __syncthreads();

    // phase 2: exclusive scan of 16
    if (tid == 0) {
        int acc = 0;
#pragma unroll
        for (int r = 0; r < 16; ++r) {
            soff[r] = acc;
            scur[r] = acc;
            acc += scnt[r];
        }
    }
    __syncthreads();

    // phase 3: scatter src ids into per-node lists, dense from LDS
    for (int i = tid; i < cnt; i += 256) {
        int p = plist[i];
        int pos = atomicAdd(&scur[p >> 17], 1);
        slist[pos] = p & 0x1FFFF;
    }
    __syncthreads();

    // phase 4: per-node register gather; wave wv owns nodes wv, wv+4, wv+8, wv+12
    for (int r = wv; r < 16; r += 4) {
        const int node = b * 16 + r;
        const int s = soff[r];
        const int d = scnt[r];
        float acc = 0.f;
        int j = 0;
        for (; j + 8 <= d; j += 8) {
            int c0 = slist[s + j + 0], c1 = slist[s + j + 1];
            int c2 = slist[s + j + 2], c3 = slist[s + j + 3];
            int c4 = slist[s + j + 4], c5 = slist[s + j + 5];
            int c6 = slist[s + j + 6], c7 = slist[s + j + 7];
            float v0 = x[(size_t)c0 * 64 + lane];
            float v1 = x[(size_t)c1 * 64 + lane];
            float v2 = x[(size_t)c2 * 64 + lane];
            float v3 = x[(size_t)c3 * 64 + lane];
            float v4 = x[(size_t)c4 * 64 + lane];
            float v5 = x[(size_t)c5 * 64 + lane];
            float v6 = x[(size_t)c6 * 64 + lane];
            float v7 = x[(size_t)c7 * 64 + lane];
            acc += ((v0 + v1) + (v2 + v3)) + ((v4 + v5) + (v6 + v7));
        }
        if (j + 4 <= d) {
            int c0 = slist[s + j + 0], c1 = slist[s + j + 1];
            int c2 = slist[s + j + 2], c3 = slist[s + j + 3];
            float v0 = x[(size_t)c0 * 64 + lane];
            float v1 = x[(size_t)c1 * 64 + lane];
            float v2 = x[(size_t)c2 * 64 + lane];
            float v3 = x[(size_t)c3 * 64 + lane];
            acc += (v0 + v1) + (v2 + v3);
            j += 4;
        }
        for (; j < d; ++j) acc += x[(size_t)slist[s + j] * 64 + lane];

        const float inv = 1.0f / fmaxf((float)d, 1.0f);
        if (L1) {
            outp[(size_t)node * 64 + lane] = acc * inv;
        } else {
            outp[(size_t)node * 64 + lane] =
                acc * inv + hz[(size_t)node * 64 + lane] + bias[lane];
        }
    }
}

// ---------------- fused 2-layer GEMM: 128 nodes x 128 outs per block ----------------
// GEMM1: h = relu(cat(agg,emb) @ cat_c(w1l,w1r)^T + b1)   (h kept in LDS only)
// GEMM2: p2 = h @ w2l^T (outs 0..63), hz = h @ w2r^T (outs 64..127)
__global__ void __launch_bounds__(512) gemm_fused_kernel(
        const float* __restrict__ agg, const float* __restrict__ emb,
        const float* __restrict__ w1l, const float* __restrict__ w1r,
        const float* __restrict__ b1,
        const float* __restrict__ w2l, const float* __restrict__ w2r,
        float* __restrict__ p2, float* __restrict__ hz) {
    __shared__ float lds_x[64 * XS];  // [c_local][node_local]; reused as hbuf in GEMM2
    __shared__ float lds_w[64 * XS];  // [c_local][o]

    const int tid = threadIdx.x;
    const int n_base = blockIdx.x * 128;

    const int ng = tid & 31;   // nodes 4*ng .. 4*ng+3
    const int og = tid >> 5;   // outs  8*og .. 8*og+7
    const int o0 = og * 8;

    float acc1[4][8];
#pragma unroll
    for (int i = 0; i < 4; ++i)
#pragma unroll
        for (int j = 0; j < 8; ++j) acc1[i][j] = 0.f;

    // ================= GEMM 1 =================
#pragma unroll
    for (int half = 0; half < 2; ++half) {
        // stage W1 half (transposed): lds_w[c][o]; row o = cat(w1l[o], w1r[o])
        {
            int o = tid >> 2;
            int wslot = tid & 3;
#pragma unroll
            for (int k = 0; k < 4; ++k) {
                int s = wslot + 4 * k;   // float4 slot 0..15
                int c4 = s * 4;
                float4 v = (half == 0) ? ((const float4*)w1l)[o * 16 + s]
                                       : ((const float4*)w1r)[o * 16 + s];
                lds_w[(c4 + 0) * XS + o] = v.x;
                lds_w[(c4 + 1) * XS + o] = v.y;
                lds_w[(c4 + 2) * XS + o] = v.z;
                lds_w[(c4 + 3) * XS + o] = v.w;
            }
        }
        // stage X half (transposed): lds_x[c][n]; X = cat(agg, emb)
        {
            int nl = tid >> 2;
            int cslot = tid & 3;
            int n = n_base + nl;
            bool ok = n < NN;
#pragma unroll
            for (int k = 0; k < 4; ++k) {
                int s = cslot + 4 * k;   // 0..15
                int c4 = s * 4;
                float4 v = make_float4(0.f, 0.f, 0.f, 0.f);
                if (ok) {
                    v = (half == 0) ? ((const float4*)agg)[(size_t)n * 16 + s]
                                    : ((const float4*)emb)[(size_t)n * 16 + s];
                }
                lds_x[(c4 + 0) * XS + nl] = v.x;
                lds_x[(c4 + 1) * XS + nl] = v.y;
                lds_x[(c4 + 2) * XS + nl] = v.z;
                lds_x[(c4 + 3) * XS + nl] = v.w;
            }
        }
        __syncthreads();

#pragma unroll 2
        for (int c = 0; c < 64; ++c) {
            float4 xv = *(const float4*)&lds_x[c * XS + ng * 4];
            float4 w0 = *(const float4*)&lds_w[c * XS + o0];
            float4 w1 = *(const float4*)&lds_w[c * XS + o0 + 4];
            float xr[4] = {xv.x, xv.y, xv.z, xv.w};
            float wr[8] = {w0.x, w0.y, w0.z, w0.w, w1.x, w1.y, w1.z, w1.w};
#pragma unroll
            for (int i = 0; i < 4; ++i)
#pragma unroll
                for (int j = 0; j < 8; ++j) acc1[i][j] += xr[i] * wr[j];
        }
        __syncthreads();
    }

    // bias for this thread's h channels
    float b1v[8];
#pragma unroll
    for (int j = 0; j < 8; ++j) b1v[j] = b1[o0 + j];

    float acc2[4][8];
#pragma unroll
    for (int i = 0; i < 4; ++i)
#pragma unroll
        for (int j = 0; j < 8; ++j) acc2[i][j] = 0.f;

    // ================= GEMM 2 (h lives in lds_x) =================
#pragma unroll
    for (int kh = 0; kh < 2; ++kh) {
        // write h channels [kh*64, kh*64+64) into hbuf (= lds_x), transposed [c][n]
        if ((og >> 3) == kh) {
            int cb = o0 - kh * 64;   // 0..56
#pragma unroll
            for (int j = 0; j < 8; ++j) {
                float4 hv = make_float4(
                    fmaxf(acc1[0][j] + b1v[j], 0.f),
                    fmaxf(acc1[1][j] + b1v[j], 0.f),
                    fmaxf(acc1[2][j] + b1v[j], 0.f),
                    fmaxf(acc1[3][j] + b1v[j], 0.f));
                *(float4*)&lds_x[(cb + j) * XS + ng * 4] = hv;
            }
        }
        // stage W2 half kh: row o: o<64 -> w2l[o], o>=64 -> w2r[o-64]
        {
            int o = tid >> 2;
            int wslot = tid & 3;
#pragma unroll
            for (int k = 0; k < 4; ++k) {
                int s = wslot + 4 * k;   // 0..15
                int cg4 = kh * 16 + s;   // global c float4 slot
                float4 v = (o < 64) ? ((const float4*)w2l)[o * 32 + cg4]
                                    : ((const float4*)w2r)[(o - 64) * 32 + cg4];
                int c4 = s * 4;
                lds_w[(c4 + 0) * XS + o] = v.x;
                lds_w[(c4 + 1) * XS + o] = v.y;
                lds_w[(c4 + 2) * XS + o] = v.z;
                lds_w[(c4 + 3) * XS + o] = v.w;
            }
        }
        __syncthreads();

#pragma unroll 2
        for (int c = 0; c < 64; ++c) {
            float4 xv = *(const float4*)&lds_x[c * XS + ng * 4];
            float4 w0 = *(const float4*)&lds_w[c * XS + o0];
            float4 w1 = *(const float4*)&lds_w[c * XS + o0 + 4];
            float xr[4] = {xv.x, xv.y, xv.z, xv.w};
            float wr[8] = {w0.x, w0.y, w0.z, w0.w, w1.x, w1.y, w1.z, w1.w};
#pragma unroll
            for (int i = 0; i < 4; ++i)
#pragma unroll
                for (int j = 0; j < 8; ++j) acc2[i][j] += xr[i] * wr[j];
        }
        __syncthreads();
    }

    // epilogue: og<8 -> p2, og>=8 -> hz
    {
        float* dstp = (og < 8) ? p2 : hz;
        int ob = (og < 8) ? o0 : (o0 - 64);
#pragma unroll
        for (int i = 0; i < 4; ++i) {
            int n = n_base + ng * 4 + i;
            if (n >= NN) continue;
            float4 lo = make_float4(acc2[i][0], acc2[i][1], acc2[i][2], acc2[i][3]);
            float4 hi = make_float4(acc2[i][4], acc2[i][5], acc2[i][6], acc2[i][7]);
            ((float4*)dstp)[(size_t)n * 16 + (ob >> 2)] = lo;
            ((float4*)dstp)[(size_t)n * 16 + (ob >> 2) + 1] = hi;
        }
    }
}

// ---------------- decode: out[k] = dot(z[a[k]], z[b[k]]) ----------------
__global__ void decode_kernel(const int* __restrict__ a, const int* __restrict__ b,
                              const float* __restrict__ z, float* __restrict__ out) {
    int t = blockIdx.x * blockDim.x + threadIdx.x;
    int k = t >> 4;
    int q = t & 15;
    if (k >= NL) return;
    int ia = a[k], ib = b[k];
    float4 va = ((const float4*)z)[ia * 16 + q];
    float4 vb = ((const float4*)z)[ib * 16 + q];
    float s = va.x * vb.x + va.y * vb.y + va.z * vb.z + va.w * vb.w;
    s += __shfl_xor(s, 1, 64);
    s += __shfl_xor(s, 2, 64);
    s += __shfl_xor(s, 4, 64);
    s += __shfl_xor(s, 8, 64);
    if (q == 0) out[k] = s;
}

extern "C" void kernel_launch(void* const* d_in, const int* in_sizes, int n_in,
                              void* d_out, int out_size, void* d_ws, size_t ws_size,
                              hipStream_t stream) {
    const float* emb = (const float*)d_in[0];
    const float* w1l = (const float*)d_in[1];
    const float* w1r = (const float*)d_in[2];
    const float* b1  = (const float*)d_in[3];
    const float* w2l = (const float*)d_in[4];
    const float* w2r = (const float*)d_in[5];
    const float* b2  = (const float*)d_in[6];
    const int*   ei  = (const int*)d_in[7];
    const int*   eli = (const int*)d_in[8];
    float* out = (float*)d_out;

    // workspace layout (~103 MB)
    int* bcnt    = (int*)d_ws;                                // NG*BSTR = 50,176
    int* tmp     = bcnt + NG * BSTR;                          // NG*NBUK*CAPG = 6,400,000
    float* agg   = (float*)(tmp + (size_t)NG * NBUK * CAPG);  // NN*64 (reused as z)
    float* p2    = agg + (size_t)NN * 64;                     // NN*64
    float* hz    = p2 + (size_t)NN * 64;                      // NN*64
    float* z     = agg;   // agg fully consumed by gemm_fused before z is written

    const int* src = ei;
    const int* dst = ei + NE;

    hipMemsetAsync(bcnt, 0, (size_t)NG * BSTR * sizeof(int), stream);

    // bucket edges by dst>>4 into per-XCD private lists
    bucket16_kernel<<<(NE + 255) / 256, 256, 0, stream>>>(src, dst, bcnt, tmp);

    const int NT = (NN + 127) / 128;  // 782 tiles

    // layer 1 aggregation: agg = mean-gather(emb)
    agg16_kernel<true><<<NBUK, 256, 0, stream>>>(bcnt, tmp, emb, nullptr, nullptr, agg);

    // fused layers: h = relu(cat(agg,emb)@cat(w1l,w1r)^T + b1); {p2,hz} = h@{w2l,w2r}^T
    gemm_fused_kernel<<<NT, 512, 0, stream>>>(agg, emb, w1l, w1r, b1, w2l, w2r, p2, hz);

    // layer 2 aggregation + fuse: z = mean-gather(p2) + hz + b2
    agg16_kernel<false><<<NBUK, 256, 0, stream>>>(bcnt, tmp, p2, hz, b2, z);

    // decode
    decode_kernel<<<(NL * 16 + 255) / 256, 256, 0, stream>>>(eli, eli + NL, z, out);
}

// Round 13
// 320.401 us; speedup vs baseline: 1.1024x; 1.0249x over previous
//
#include <hip/hip_runtime.h>

#define NN   100000
#define EMB  64
#define HID  128
#define OUTD 64
#define NE   1600000
#define NL   200000
#define NBUK 6250     // NN/16 buckets of exactly 16 nodes
#define NG   8        // per-XCD privatized copies
#define CAPG 128      // per-XCD bucket capacity (pow2 for shift/mask); E=32
#define BSTR 6272     // padded per-group bcnt stride

__device__ __forceinline__ unsigned xcc_id() {
    unsigned v;
    asm volatile("s_getreg_b32 %0, hwreg(HW_REG_XCC_ID)" : "=s"(v));
    return v & (NG - 1);
}

// ---------------- bucket edges by dst>>4 into per-XCD private buckets ----------------
__global__ void bucket16_kernel(const int* __restrict__ src, const int* __restrict__ dst,
                                int* __restrict__ bcnt, int* __restrict__ tmp) {
    int i = blockIdx.x * blockDim.x + threadIdx.x;
    if (i >= NE) return;
    unsigned g = xcc_id();          // wave-uniform physical XCD id
    int d = dst[i];
    int s = src[i];
    int b = d >> 4;
    int pos = atomicAdd(&bcnt[g * BSTR + b], 1);
    if (pos < CAPG) tmp[((size_t)g * NBUK + b) * CAPG + pos] = ((d & 15) << 17) | s;
}

// ---------------- per-bucket aggregation: flatten lists -> micro-CSR -> reg gather ----
// L1=true : out[i] = (1/max(deg,1)) * sum_{j in N(i)} x[j]
// L1=false: out[i] = (1/max(deg,1)) * sum x[j] + hz[i] + bias   (fused z)
template<bool L1>
__global__ void __launch_bounds__(256) agg16_kernel(
        const int* __restrict__ bcnt, const int* __restrict__ tmp,
        const float* __restrict__ x,
        const float* __restrict__ hz, const float* __restrict__ bias,
        float* __restrict__ outp) {
    __shared__ int cgs[NG];
    __shared__ int goff[NG];
    __shared__ int total;
    __shared__ int scnt[16];
    __shared__ int soff[16];
    __shared__ int scur[16];
    __shared__ int plist[NG * CAPG];   // flattened packed entries (dense)
    __shared__ int slist[NG * CAPG];   // grouped-by-node src ids

    const int b    = blockIdx.x;
    const int tid  = threadIdx.x;
    const int lane = tid & 63;
    const int wv   = tid >> 6;         // 0..3

    if (tid < NG) cgs[tid] = min(bcnt[tid * BSTR + b], CAPG);
    if (tid < 16) scnt[tid] = 0;
    __syncthreads();

    if (tid == 0) {
        int acc = 0;
#pragma unroll
        for (int g = 0; g < NG; ++g) { int c = cgs[g]; goff[g] = acc; acc += c; }
        total = acc;
    }
    __syncthreads();

    // flatten: one dense coalesced read of all 8 sub-lists into plist
    for (int t = tid; t < NG * CAPG; t += 256) {
        int g = t >> 7;          // CAPG = 128
        int i = t & (CAPG - 1);
        if (i < cgs[g])
            plist[goff[g] + i] = tmp[((size_t)g * NBUK + b) * CAPG + i];
    }
    __syncthreads();

    const int cnt = total;

    // phase 1: per-node counts (= degree), dense from LDS
    for (int i = tid; i < cnt; i += 256)
        atomicAdd(&scnt[plist[i] >> 17], 1);
    __syncthreads();

    // phase 2: exclusive scan of 16
    if (tid == 0) {
        int acc = 0;
#pragma unroll
        for (int r = 0; r < 16; ++r) {
            soff[r] = acc;
            scur[r] = acc;
            acc += scnt[r];
        }
    }
    __syncthreads();

    // phase 3: scatter src ids into per-node lists, dense from LDS
    for (int i = tid; i < cnt; i += 256) {
        int p = plist[i];
        int pos = atomicAdd(&scur[p >> 17], 1);
        slist[pos] = p & 0x1FFFF;
    }
    __syncthreads();

    // phase 4: per-node register gather; wave wv owns nodes wv, wv+4, wv+8, wv+12
    for (int r = wv; r < 16; r += 4) {
        const int node = b * 16 + r;
        const int s = soff[r];
        const int d = scnt[r];
        float acc = 0.f;
        int j = 0;
        for (; j + 8 <= d; j += 8) {
            int c0 = slist[s + j + 0], c1 = slist[s + j + 1];
            int c2 = slist[s + j + 2], c3 = slist[s + j + 3];
            int c4 = slist[s + j + 4], c5 = slist[s + j + 5];
            int c6 = slist[s + j + 6], c7 = slist[s + j + 7];
            float v0 = x[(size_t)c0 * 64 + lane];
            float v1 = x[(size_t)c1 * 64 + lane];
            float v2 = x[(size_t)c2 * 64 + lane];
            float v3 = x[(size_t)c3 * 64 + lane];
            float v4 = x[(size_t)c4 * 64 + lane];
            float v5 = x[(size_t)c5 * 64 + lane];
            float v6 = x[(size_t)c6 * 64 + lane];
            float v7 = x[(size_t)c7 * 64 + lane];
            acc += ((v0 + v1) + (v2 + v3)) + ((v4 + v5) + (v6 + v7));
        }
        if (j + 4 <= d) {
            int c0 = slist[s + j + 0], c1 = slist[s + j + 1];
            int c2 = slist[s + j + 2], c3 = slist[s + j + 3];
            float v0 = x[(size_t)c0 * 64 + lane];
            float v1 = x[(size_t)c1 * 64 + lane];
            float v2 = x[(size_t)c2 * 64 + lane];
            float v3 = x[(size_t)c3 * 64 + lane];
            acc += (v0 + v1) + (v2 + v3);
            j += 4;
        }
        for (; j < d; ++j) acc += x[(size_t)slist[s + j] * 64 + lane];

        const float inv = 1.0f / fmaxf((float)d, 1.0f);
        if (L1) {
            outp[(size_t)node * 64 + lane] = acc * inv;
        } else {
            outp[(size_t)node * 64 + lane] =
                acc * inv + hz[(size_t)node * 64 + lane] + bias[lane];
        }
    }
}

// ---------------- fused 2-layer GEMM: 128 nodes x 128 outs, 256 thr, 8x8 per thread ----
// GEMM1: h = relu(cat(agg,emb) @ cat_c(w1l,w1r)^T + b1)   (h kept in LDS only)
// GEMM2: p2 = h @ w2l^T (outs 0..63), hz = h @ w2r^T (outs 64..127)
// Thread (nl,og): nodes {nl*4+i, 64+nl*4+i}, outs {og*4+j, 64+og*4+j}, i,j in 0..3
__global__ void __launch_bounds__(256) gemm_fused_kernel(
        const float* __restrict__ agg, const float* __restrict__ emb,
        const float* __restrict__ w1l, const float* __restrict__ w1r,
        const float* __restrict__ b1,
        const float* __restrict__ w2l, const float* __restrict__ w2r,
        float* __restrict__ p2, float* __restrict__ hz) {
    __shared__ float lds_x[64 * 128];  // [c_local][node_local]; reused as hbuf in GEMM2
    __shared__ float lds_w[64 * 128];  // [c_local][o]

    const int tid = threadIdx.x;
    const int n_base = blockIdx.x * 128;
    const int nl = tid & 15;   // node group
    const int og = tid >> 4;   // out group 0..15

    float acc1[8][8];
#pragma unroll
    for (int i = 0; i < 8; ++i)
#pragma unroll
        for (int j = 0; j < 8; ++j) acc1[i][j] = 0.f;

    // ================= GEMM 1 =================
#pragma unroll
    for (int half = 0; half < 2; ++half) {
        {   // stage W1 half (transposed): lds_w[c][o]; row o = cat(w1l[o], w1r[o])
            const float4* Wsrc = (half == 0) ? (const float4*)w1l : (const float4*)w1r;
            int o = tid >> 1, ws = tid & 1;
#pragma unroll
            for (int k = 0; k < 8; ++k) {
                int s = ws + 2 * k;     // float4 slot 0..15
                float4 v = Wsrc[o * 16 + s];
                lds_w[(4 * s + 0) * 128 + o] = v.x;
                lds_w[(4 * s + 1) * 128 + o] = v.y;
                lds_w[(4 * s + 2) * 128 + o] = v.z;
                lds_w[(4 * s + 3) * 128 + o] = v.w;
            }
        }
        {   // stage X half (transposed): lds_x[c][n]; X = cat(agg, emb)
            const float4* Xsrc = (half == 0) ? (const float4*)agg : (const float4*)emb;
            int nl2 = tid >> 1, cs = tid & 1;
            int n = n_base + nl2;
            bool ok = n < NN;
#pragma unroll
            for (int k = 0; k < 8; ++k) {
                int s = cs + 2 * k;     // 0..15
                float4 v = ok ? Xsrc[(size_t)n * 16 + s] : make_float4(0.f, 0.f, 0.f, 0.f);
                lds_x[(4 * s + 0) * 128 + nl2] = v.x;
                lds_x[(4 * s + 1) * 128 + nl2] = v.y;
                lds_x[(4 * s + 2) * 128 + nl2] = v.z;
                lds_x[(4 * s + 3) * 128 + nl2] = v.w;
            }
        }
        __syncthreads();

#pragma unroll 2
        for (int c = 0; c < 64; ++c) {
            float4 xa = *(const float4*)&lds_x[c * 128 + nl * 4];
            float4 xb = *(const float4*)&lds_x[c * 128 + 64 + nl * 4];
            float4 wa = *(const float4*)&lds_w[c * 128 + og * 4];
            float4 wb = *(const float4*)&lds_w[c * 128 + 64 + og * 4];
            float xr[8] = {xa.x, xa.y, xa.z, xa.w, xb.x, xb.y, xb.z, xb.w};
            float wr[8] = {wa.x, wa.y, wa.z, wa.w, wb.x, wb.y, wb.z, wb.w};
#pragma unroll
            for (int i = 0; i < 8; ++i)
#pragma unroll
                for (int j = 0; j < 8; ++j) acc1[i][j] += xr[i] * wr[j];
        }
        __syncthreads();
    }

    float b1v[8];
#pragma unroll
    for (int j = 0; j < 4; ++j) b1v[j] = b1[og * 4 + j];
#pragma unroll
    for (int j = 4; j < 8; ++j) b1v[j] = b1[64 + og * 4 + (j - 4)];

    float acc2[8][8];
#pragma unroll
    for (int i = 0; i < 8; ++i)
#pragma unroll
        for (int j = 0; j < 8; ++j) acc2[i][j] = 0.f;

    // ================= GEMM 2 (h lives in lds_x) =================
#pragma unroll
    for (int kh = 0; kh < 2; ++kh) {
        // write h channels [kh*64, kh*64+64) into hbuf (= lds_x), transposed [c][n]
#pragma unroll
        for (int jj = 0; jj < 4; ++jj) {
            int j = kh * 4 + jj;       // acc1 col: j<4 -> ch og*4+jj; j>=4 -> ch 64+og*4+jj
            int cl = og * 4 + jj;      // local channel within half
            float bb = b1v[j];
            float4 v0 = make_float4(fmaxf(acc1[0][j] + bb, 0.f), fmaxf(acc1[1][j] + bb, 0.f),
                                    fmaxf(acc1[2][j] + bb, 0.f), fmaxf(acc1[3][j] + bb, 0.f));
            float4 v1 = make_float4(fmaxf(acc1[4][j] + bb, 0.f), fmaxf(acc1[5][j] + bb, 0.f),
                                    fmaxf(acc1[6][j] + bb, 0.f), fmaxf(acc1[7][j] + bb, 0.f));
            *(float4*)&lds_x[cl * 128 + nl * 4] = v0;
            *(float4*)&lds_x[cl * 128 + 64 + nl * 4] = v1;
        }
        {   // stage W2 half kh: row o: o<64 -> w2l[o], o>=64 -> w2r[o-64]
            int o = tid >> 1, ws = tid & 1;
#pragma unroll
            for (int k = 0; k < 8; ++k) {
                int s = ws + 2 * k;     // local c float4 slot 0..15
                int cg4 = kh * 16 + s;  // global c float4 slot
                float4 v = (o < 64) ? ((const float4*)w2l)[o * 32 + cg4]
                                    : ((const float4*)w2r)[(o - 64) * 32 + cg4];
                lds_w[(4 * s + 0) * 128 + o] = v.x;
                lds_w[(4 * s + 1) * 128 + o] = v.y;
                lds_w[(4 * s + 2) * 128 + o] = v.z;
                lds_w[(4 * s + 3) * 128 + o] = v.w;
            }
        }
        __syncthreads();

#pragma unroll 2
        for (int c = 0; c < 64; ++c) {
            float4 xa = *(const float4*)&lds_x[c * 128 + nl * 4];
            float4 xb = *(const float4*)&lds_x[c * 128 + 64 + nl * 4];
            float4 wa = *(const float4*)&lds_w[c * 128 + og * 4];
            float4 wb = *(const float4*)&lds_w[c * 128 + 64 + og * 4];
            float xr[8] = {xa.x, xa.y, xa.z, xa.w, xb.x, xb.y, xb.z, xb.w};
            float wr[8] = {wa.x, wa.y, wa.z, wa.w, wb.x, wb.y, wb.z, wb.w};
#pragma unroll
            for (int i = 0; i < 8; ++i)
#pragma unroll
                for (int j = 0; j < 8; ++j) acc2[i][j] += xr[i] * wr[j];
        }
        __syncthreads();
    }

    // epilogue: out cols og*4..+3 -> p2, 64+og*4..+3 -> hz
#pragma unroll
    for (int i = 0; i < 8; ++i) {
        int n = n_base + ((i < 4) ? (nl * 4 + i) : (64 + nl * 4 + (i - 4)));
        if (n >= NN) continue;
        ((float4*)p2)[(size_t)n * 16 + og] =
            make_float4(acc2[i][0], acc2[i][1], acc2[i][2], acc2[i][3]);
        ((float4*)hz)[(size_t)n * 16 + og] =
            make_float4(acc2[i][4], acc2[i][5], acc2[i][6], acc2[i][7]);
    }
}

// ---------------- decode: out[k] = dot(z[a[k]], z[b[k]]) ----------------
__global__ void decode_kernel(const int* __restrict__ a, const int* __restrict__ b,
                              const float* __restrict__ z, float* __restrict__ out) {
    int t = blockIdx.x * blockDim.x + threadIdx.x;
    int k = t >> 4;
    int q = t & 15;
    if (k >= NL) return;
    int ia = a[k], ib = b[k];
    float4 va = ((const float4*)z)[ia * 16 + q];
    float4 vb = ((const float4*)z)[ib * 16 + q];
    float s = va.x * vb.x + va.y * vb.y + va.z * vb.z + va.w * vb.w;
    s += __shfl_xor(s, 1, 64);
    s += __shfl_xor(s, 2, 64);
    s += __shfl_xor(s, 4, 64);
    s += __shfl_xor(s, 8, 64);
    if (q == 0) out[k] = s;
}

extern "C" void kernel_launch(void* const* d_in, const int* in_sizes, int n_in,
                              void* d_out, int out_size, void* d_ws, size_t ws_size,
                              hipStream_t stream) {
    const float* emb = (const float*)d_in[0];
    const float* w1l = (const float*)d_in[1];
    const float* w1r = (const float*)d_in[2];
    const float* b1  = (const float*)d_in[3];
    const float* w2l = (const float*)d_in[4];
    const float* w2r = (const float*)d_in[5];
    const float* b2  = (const float*)d_in[6];
    const int*   ei  = (const int*)d_in[7];
    const int*   eli = (const int*)d_in[8];
    float* out = (float*)d_out;

    // workspace layout (~103 MB)
    int* bcnt    = (int*)d_ws;                                // NG*BSTR = 50,176
    int* tmp     = bcnt + NG * BSTR;                          // NG*NBUK*CAPG = 6,400,000
    float* agg   = (float*)(tmp + (size_t)NG * NBUK * CAPG);  // NN*64 (reused as z)
    float* p2    = agg + (size_t)NN * 64;                     // NN*64
    float* hz    = p2 + (size_t)NN * 64;                      // NN*64
    float* z     = agg;   // agg fully consumed by gemm_fused before z is written

    const int* src = ei;
    const int* dst = ei + NE;

    hipMemsetAsync(bcnt, 0, (size_t)NG * BSTR * sizeof(int), stream);

    // bucket edges by dst>>4 into per-XCD private lists
    bucket16_kernel<<<(NE + 255) / 256, 256, 0, stream>>>(src, dst, bcnt, tmp);

    const int NT = (NN + 127) / 128;  // 782 tiles

    // layer 1 aggregation: agg = mean-gather(emb)
    agg16_kernel<true><<<NBUK, 256, 0, stream>>>(bcnt, tmp, emb, nullptr, nullptr, agg);

    // fused layers: h = relu(cat(agg,emb)@cat(w1l,w1r)^T + b1); {p2,hz} = h@{w2l,w2r}^T
    gemm_fused_kernel<<<NT, 256, 0, stream>>>(agg, emb, w1l, w1r, b1, w2l, w2r, p2, hz);

    // layer 2 aggregation + fuse: z = mean-gather(p2) + hz + b2
    agg16_kernel<false><<<NBUK, 256, 0, stream>>>(bcnt, tmp, p2, hz, b2, z);

    // decode
    decode_kernel<<<(NL * 16 + 255) / 256, 256, 0, stream>>>(eli, eli + NL, z, out);
}

// Round 14
// 255.497 us; speedup vs baseline: 1.3825x; 1.2540x over previous
//
#include <hip/hip_runtime.h>

#define NN   100000
#define EMB  64
#define HID  128
#define OUTD 64
#define NE   1600000
#define NL   200000
#define NBUK 6250     // NN/16 buckets of exactly 16 nodes
#define NG   8        // per-XCD privatized copies
#define CAPG 128      // per-XCD bucket capacity (pow2); E=32
#define BSTR 6272     // padded per-group bcnt stride

typedef __attribute__((ext_vector_type(4))) float f32x4;
typedef __attribute__((ext_vector_type(8))) short s16x8;
typedef __attribute__((ext_vector_type(4))) unsigned short us4;

__device__ __forceinline__ unsigned short f2bf(float f) {
    unsigned u = __float_as_uint(f);
    u += 0x7FFFu + ((u >> 16) & 1u);   // RNE
    return (unsigned short)(u >> 16);
}
__device__ __forceinline__ float bf2f(unsigned short h) {
    return __uint_as_float(((unsigned)h) << 16);
}

__device__ __forceinline__ unsigned xcc_id() {
    unsigned v;
    asm volatile("s_getreg_b32 %0, hwreg(HW_REG_XCC_ID)" : "=s"(v));
    return v & (NG - 1);
}

// ---------------- bucket edges by dst>>4 into per-XCD private buckets ----------------
__global__ void bucket16_kernel(const int* __restrict__ src, const int* __restrict__ dst,
                                int* __restrict__ bcnt, int* __restrict__ tmp) {
    int i = blockIdx.x * blockDim.x + threadIdx.x;
    if (i >= NE) return;
    unsigned g = xcc_id();
    int d = dst[i];
    int s = src[i];
    int b = d >> 4;
    int pos = atomicAdd(&bcnt[g * BSTR + b], 1);
    if (pos < CAPG) tmp[((size_t)g * NBUK + b) * CAPG + pos] = ((d & 15) << 17) | s;
}

// ---------------- converts ----------------
__global__ void conv_emb_kernel(const float* __restrict__ emb, unsigned short* __restrict__ embb) {
    int i = blockIdx.x * blockDim.x + threadIdx.x;   // over NN*64/4
    if (i >= NN * 16) return;
    float4 v = ((const float4*)emb)[i];
    us4 o;
    o.x = f2bf(v.x); o.y = f2bf(v.y); o.z = f2bf(v.z); o.w = f2bf(v.w);
    ((us4*)embb)[i] = o;
}

__global__ void conv_w_kernel(const float* __restrict__ w1l, const float* __restrict__ w1r,
                              const float* __restrict__ w2l, const float* __restrict__ w2r,
                              unsigned short* __restrict__ w1cat, unsigned short* __restrict__ w2cat) {
    int t = blockIdx.x * blockDim.x + threadIdx.x;
    if (t >= 128 * 128) return;
    int o = t >> 7, k = t & 127;
    w1cat[t] = f2bf(k < 64 ? w1l[o * 64 + k] : w1r[o * 64 + (k - 64)]);
    w2cat[t] = f2bf(o < 64 ? w2l[o * 128 + k] : w2r[(o - 64) * 128 + k]);
}

// ---------------- per-bucket aggregation: flatten -> micro-CSR -> reg gather --------
// L1=true : outb[i] = bf16( (1/max(deg,1)) * sum_{j in N(i)} xf[j] )      (fp32 input)
// L1=false: outf[i] = (1/max(deg,1)) * sum bf2f(xb[j]) + hz[i] + bias     (bf16 input)
template<bool L1>
__global__ void __launch_bounds__(256) agg16_kernel(
        const int* __restrict__ bcnt, const int* __restrict__ tmp,
        const float* __restrict__ xf, const unsigned short* __restrict__ xb,
        const float* __restrict__ hz, const float* __restrict__ bias,
        unsigned short* __restrict__ outb, float* __restrict__ outf) {
    __shared__ int cgs[NG];
    __shared__ int goff[NG];
    __shared__ int total;
    __shared__ int scnt[16];
    __shared__ int soff[16];
    __shared__ int scur[16];
    __shared__ int plist[NG * CAPG];
    __shared__ int slist[NG * CAPG];

    const int b    = blockIdx.x;
    const int tid  = threadIdx.x;
    const int lane = tid & 63;
    const int wv   = tid >> 6;

    if (tid < NG) cgs[tid] = min(bcnt[tid * BSTR + b], CAPG);
    if (tid < 16) scnt[tid] = 0;
    __syncthreads();

    if (tid == 0) {
        int acc = 0;
#pragma unroll
        for (int g = 0; g < NG; ++g) { int c = cgs[g]; goff[g] = acc; acc += c; }
        total = acc;
    }
    __syncthreads();

    for (int t = tid; t < NG * CAPG; t += 256) {
        int g = t >> 7;
        int i = t & (CAPG - 1);
        if (i < cgs[g])
            plist[goff[g] + i] = tmp[((size_t)g * NBUK + b) * CAPG + i];
    }
    __syncthreads();

    const int cnt = total;
    for (int i = tid; i < cnt; i += 256)
        atomicAdd(&scnt[plist[i] >> 17], 1);
    __syncthreads();

    if (tid == 0) {
        int acc = 0;
#pragma unroll
        for (int r = 0; r < 16; ++r) {
            soff[r] = acc;
            scur[r] = acc;
            acc += scnt[r];
        }
    }
    __syncthreads();

    for (int i = tid; i < cnt; i += 256) {
        int p = plist[i];
        int pos = atomicAdd(&scur[p >> 17], 1);
        slist[pos] = p & 0x1FFFF;
    }
    __syncthreads();

#define LDX(c) (L1 ? xf[(size_t)(c) * 64 + lane] : bf2f(xb[(size_t)(c) * 64 + lane]))
    for (int r = wv; r < 16; r += 4) {
        const int node = b * 16 + r;
        const int s = soff[r];
        const int d = scnt[r];
        float acc = 0.f;
        int j = 0;
        for (; j + 8 <= d; j += 8) {
            int c0 = slist[s + j + 0], c1 = slist[s + j + 1];
            int c2 = slist[s + j + 2], c3 = slist[s + j + 3];
            int c4 = slist[s + j + 4], c5 = slist[s + j + 5];
            int c6 = slist[s + j + 6], c7 = slist[s + j + 7];
            float v0 = LDX(c0), v1 = LDX(c1), v2 = LDX(c2), v3 = LDX(c3);
            float v4 = LDX(c4), v5 = LDX(c5), v6 = LDX(c6), v7 = LDX(c7);
            acc += ((v0 + v1) + (v2 + v3)) + ((v4 + v5) + (v6 + v7));
        }
        if (j + 4 <= d) {
            int c0 = slist[s + j + 0], c1 = slist[s + j + 1];
            int c2 = slist[s + j + 2], c3 = slist[s + j + 3];
            float v0 = LDX(c0), v1 = LDX(c1), v2 = LDX(c2), v3 = LDX(c3);
            acc += (v0 + v1) + (v2 + v3);
            j += 4;
        }
        for (; j < d; ++j) acc += LDX(slist[s + j]);

        const float inv = 1.0f / fmaxf((float)d, 1.0f);
        if (L1) {
            outb[(size_t)node * 64 + lane] = f2bf(acc * inv);
        } else {
            outf[(size_t)node * 64 + lane] =
                acc * inv + hz[(size_t)node * 64 + lane] + bias[lane];
        }
    }
#undef LDX
}

// ---------------- MFMA fused 2-layer GEMM: 128 nodes/block, 4 waves, 0 barriers ------
// GEMM1: h = relu(cat(aggb,embb) @ w1cat^T + b1)  (bf16 A from global, h -> LDS bf16)
// GEMM2: p2b = bf16(h @ w2l^T), hz = h @ w2r^T    (A from LDS, B = w2cat)
// Fragment layouts (mfma_f32_16x16x32_bf16): A: lane holds A[l&15][8*(l>>4)+j];
// B: lane holds B[8*(l>>4)+j][l&15]; C/D: col=lane&15, row=(lane>>4)*4+reg [m89/m91].
__global__ void __launch_bounds__(256) gemm_mfma_kernel(
        const unsigned short* __restrict__ aggb, const unsigned short* __restrict__ embb,
        const unsigned short* __restrict__ w1cat, const float* __restrict__ b1,
        const unsigned short* __restrict__ w2cat,
        unsigned short* __restrict__ p2b, float* __restrict__ hz) {
    __shared__ unsigned short h_lds[128 * 136];   // pad 136 -> conflict-free, 16B-aligned rows

    const int tid  = threadIdx.x;
    const int lane = tid & 63;
    const int w    = tid >> 6;          // wave 0..3, owns rows [w*32, w*32+32)
    const int l15  = lane & 15;
    const int lk   = lane >> 4;         // k-chunk 0..3
    const int n_base = blockIdx.x * 128;
    const int mrow0  = w * 32;

    f32x4 acc[2][8];
#pragma unroll
    for (int mt = 0; mt < 2; ++mt)
#pragma unroll
        for (int nt = 0; nt < 8; ++nt) acc[mt][nt] = (f32x4)(0.f);

    // ================= GEMM 1 =================
#pragma unroll
    for (int ks = 0; ks < 4; ++ks) {
        const int kc = ks * 32 + lk * 8;    // 0..120
        s16x8 a[2];
#pragma unroll
        for (int mt = 0; mt < 2; ++mt) {
            int n = n_base + mrow0 + mt * 16 + l15;
            s16x8 av = (s16x8)(short)0;
            if (n < NN) {
                const unsigned short* ap = (kc < 64)
                    ? (aggb + (size_t)n * 64 + kc)
                    : (embb + (size_t)n * 64 + (kc - 64));
                av = *(const s16x8*)ap;
            }
            a[mt] = av;
        }
#pragma unroll
        for (int nt = 0; nt < 8; ++nt) {
            s16x8 bv = *(const s16x8*)(w1cat + (nt * 16 + l15) * 128 + kc);
            acc[0][nt] = __builtin_amdgcn_mfma_f32_16x16x32_bf16(a[0], bv, acc[0][nt], 0, 0, 0);
            acc[1][nt] = __builtin_amdgcn_mfma_f32_16x16x32_bf16(a[1], bv, acc[1][nt], 0, 0, 0);
        }
    }

    // epilogue 1: bias + relu -> h_lds (wave-private rows; no barrier needed)
    float b1v[8];
#pragma unroll
    for (int nt = 0; nt < 8; ++nt) b1v[nt] = b1[nt * 16 + l15];
#pragma unroll
    for (int mt = 0; mt < 2; ++mt)
#pragma unroll
        for (int nt = 0; nt < 8; ++nt) {
            f32x4 d = acc[mt][nt];
            int o = nt * 16 + l15;
            int r0 = mrow0 + mt * 16 + lk * 4;
#pragma unroll
            for (int j = 0; j < 4; ++j)
                h_lds[(r0 + j) * 136 + o] = f2bf(fmaxf(d[j] + b1v[nt], 0.f));
        }

#pragma unroll
    for (int mt = 0; mt < 2; ++mt)
#pragma unroll
        for (int nt = 0; nt < 8; ++nt) acc[mt][nt] = (f32x4)(0.f);

    // ================= GEMM 2 =================
#pragma unroll
    for (int ks = 0; ks < 4; ++ks) {
        const int kc = ks * 32 + lk * 8;
        s16x8 a[2];
#pragma unroll
        for (int mt = 0; mt < 2; ++mt)
            a[mt] = *(const s16x8*)&h_lds[(mrow0 + mt * 16 + l15) * 136 + kc];
#pragma unroll
        for (int nt = 0; nt < 8; ++nt) {
            s16x8 bv = *(const s16x8*)(w2cat + (nt * 16 + l15) * 128 + kc);
            acc[0][nt] = __builtin_amdgcn_mfma_f32_16x16x32_bf16(a[0], bv, acc[0][nt], 0, 0, 0);
            acc[1][nt] = __builtin_amdgcn_mfma_f32_16x16x32_bf16(a[1], bv, acc[1][nt], 0, 0, 0);
        }
    }

    // epilogue 2: nt<4 -> p2b (bf16), nt>=4 -> hz (fp32)
#pragma unroll
    for (int mt = 0; mt < 2; ++mt)
#pragma unroll
        for (int nt = 0; nt < 8; ++nt) {
            f32x4 d = acc[mt][nt];
            int o = nt * 16 + l15;
            int r0 = n_base + mrow0 + mt * 16 + lk * 4;
#pragma unroll
            for (int j = 0; j < 4; ++j) {
                int r = r0 + j;
                if (r >= NN) continue;
                if (nt < 4) p2b[(size_t)r * 64 + o] = f2bf(d[j]);
                else        hz[(size_t)r * 64 + (o - 64)] = d[j];
            }
        }
}

// ---------------- decode: out[k] = dot(z[a[k]], z[b[k]]) ----------------
__global__ void decode_kernel(const int* __restrict__ a, const int* __restrict__ b,
                              const float* __restrict__ z, float* __restrict__ out) {
    int t = blockIdx.x * blockDim.x + threadIdx.x;
    int k = t >> 4;
    int q = t & 15;
    if (k >= NL) return;
    int ia = a[k], ib = b[k];
    float4 va = ((const float4*)z)[ia * 16 + q];
    float4 vb = ((const float4*)z)[ib * 16 + q];
    float s = va.x * vb.x + va.y * vb.y + va.z * vb.z + va.w * vb.w;
    s += __shfl_xor(s, 1, 64);
    s += __shfl_xor(s, 2, 64);
    s += __shfl_xor(s, 4, 64);
    s += __shfl_xor(s, 8, 64);
    if (q == 0) out[k] = s;
}

extern "C" void kernel_launch(void* const* d_in, const int* in_sizes, int n_in,
                              void* d_out, int out_size, void* d_ws, size_t ws_size,
                              hipStream_t stream) {
    const float* emb = (const float*)d_in[0];
    const float* w1l = (const float*)d_in[1];
    const float* w1r = (const float*)d_in[2];
    const float* b1  = (const float*)d_in[3];
    const float* w2l = (const float*)d_in[4];
    const float* w2r = (const float*)d_in[5];
    const float* b2  = (const float*)d_in[6];
    const int*   ei  = (const int*)d_in[7];
    const int*   eli = (const int*)d_in[8];
    float* out = (float*)d_out;

    // workspace layout (~116 MB)
    int* bcnt = (int*)d_ws;                                   // NG*BSTR = 50,176 ints
    int* tmp  = bcnt + NG * BSTR;                             // NG*NBUK*CAPG = 6,400,000 ints
    unsigned short* aggb  = (unsigned short*)(tmp + (size_t)NG * NBUK * CAPG);  // NN*64 bf16
    unsigned short* embb  = aggb + (size_t)NN * 64;           // NN*64 bf16
    unsigned short* p2b   = embb + (size_t)NN * 64;           // NN*64 bf16
    unsigned short* w1cat = p2b + (size_t)NN * 64;            // 128*128 bf16
    unsigned short* w2cat = w1cat + 128 * 128;                // 128*128 bf16
    float* hz = (float*)(w2cat + 128 * 128);                  // NN*64 f32
    float* z  = hz + (size_t)NN * 64;                         // NN*64 f32

    const int* src = ei;
    const int* dst = ei + NE;

    hipMemsetAsync(bcnt, 0, (size_t)NG * BSTR * sizeof(int), stream);

    bucket16_kernel<<<(NE + 255) / 256, 256, 0, stream>>>(src, dst, bcnt, tmp);
    conv_emb_kernel<<<(NN * 16 + 255) / 256, 256, 0, stream>>>(emb, embb);
    conv_w_kernel<<<64, 256, 0, stream>>>(w1l, w1r, w2l, w2r, w1cat, w2cat);

    // layer 1 aggregation: aggb = bf16(mean-gather(emb))
    agg16_kernel<true><<<NBUK, 256, 0, stream>>>(bcnt, tmp, emb, nullptr, nullptr, nullptr,
                                                 aggb, nullptr);

    // fused MFMA layers: h = relu(cat(agg,emb)@w1cat^T + b1); {p2b, hz} = h@{w2l,w2r}^T
    const int NT = (NN + 127) / 128;  // 782
    gemm_mfma_kernel<<<NT, 256, 0, stream>>>(aggb, embb, w1cat, b1, w2cat, p2b, hz);

    // layer 2 aggregation + fuse: z = mean-gather(p2b) + hz + b2
    agg16_kernel<false><<<NBUK, 256, 0, stream>>>(bcnt, tmp, nullptr, p2b, hz, b2,
                                                  nullptr, z);

    // decode
    decode_kernel<<<(NL * 16 + 255) / 256, 256, 0, stream>>>(eli, eli + NL, z, out);
}

// Round 15
// 237.214 us; speedup vs baseline: 1.4890x; 1.0771x over previous
//
#include <hip/hip_runtime.h>

#define NN   100000
#define EMB  64
#define HID  128
#define OUTD 64
#define NE   1600000
#define NL   200000
#define NBUK 6250     // NN/16 buckets of exactly 16 nodes
#define NG   8        // per-XCD privatized copies
#define CAPG 128      // per-XCD bucket capacity (pow2); E=32
#define BSTR 6272     // padded per-group bcnt stride

typedef __attribute__((ext_vector_type(4))) float f32x4;
typedef __attribute__((ext_vector_type(8))) short s16x8;
typedef __attribute__((ext_vector_type(4))) unsigned short us4;

__device__ __forceinline__ unsigned short f2bf(float f) {
    unsigned u = __float_as_uint(f);
    u += 0x7FFFu + ((u >> 16) & 1u);   // RNE
    return (unsigned short)(u >> 16);
}
__device__ __forceinline__ float bf2f(unsigned short h) {
    return __uint_as_float(((unsigned)h) << 16);
}

__device__ __forceinline__ unsigned xcc_id() {
    unsigned v;
    asm volatile("s_getreg_b32 %0, hwreg(HW_REG_XCC_ID)" : "=s"(v));
    return v & (NG - 1);
}

// ------- bucket edges by dst>>4 into per-XCD private buckets; 4 edges/thread (ILP) ---
__global__ void bucket16_kernel(const int* __restrict__ src, const int* __restrict__ dst,
                                int* __restrict__ bcnt, int* __restrict__ tmp) {
    int i = blockIdx.x * blockDim.x + threadIdx.x;
    if (i >= NE / 4) return;
    unsigned g = xcc_id();
    int* cb = bcnt + g * BSTR;
    int4 d4 = ((const int4*)dst)[i];
    int4 s4 = ((const int4*)src)[i];
    int b0 = d4.x >> 4, b1 = d4.y >> 4, b2 = d4.z >> 4, b3 = d4.w >> 4;
    int p0 = atomicAdd(&cb[b0], 1);
    int p1 = atomicAdd(&cb[b1], 1);
    int p2 = atomicAdd(&cb[b2], 1);
    int p3 = atomicAdd(&cb[b3], 1);
    if (p0 < CAPG) tmp[((size_t)g * NBUK + b0) * CAPG + p0] = ((d4.x & 15) << 17) | s4.x;
    if (p1 < CAPG) tmp[((size_t)g * NBUK + b1) * CAPG + p1] = ((d4.y & 15) << 17) | s4.y;
    if (p2 < CAPG) tmp[((size_t)g * NBUK + b2) * CAPG + p2] = ((d4.z & 15) << 17) | s4.z;
    if (p3 < CAPG) tmp[((size_t)g * NBUK + b3) * CAPG + p3] = ((d4.w & 15) << 17) | s4.w;
}

// ---------------- converts ----------------
__global__ void conv_emb_kernel(const float* __restrict__ emb, unsigned short* __restrict__ embb) {
    int i = blockIdx.x * blockDim.x + threadIdx.x;   // over NN*64/4
    if (i >= NN * 16) return;
    float4 v = ((const float4*)emb)[i];
    us4 o;
    o.x = f2bf(v.x); o.y = f2bf(v.y); o.z = f2bf(v.z); o.w = f2bf(v.w);
    ((us4*)embb)[i] = o;
}

__global__ void conv_w_kernel(const float* __restrict__ w1l, const float* __restrict__ w1r,
                              const float* __restrict__ w2l, const float* __restrict__ w2r,
                              unsigned short* __restrict__ w1cat, unsigned short* __restrict__ w2cat) {
    int t = blockIdx.x * blockDim.x + threadIdx.x;
    if (t >= 128 * 128) return;
    int o = t >> 7, k = t & 127;
    w1cat[t] = f2bf(k < 64 ? w1l[o * 64 + k] : w1r[o * 64 + (k - 64)]);
    w2cat[t] = f2bf(o < 64 ? w2l[o * 128 + k] : w2r[(o - 64) * 128 + k]);
}

// ------- per-bucket aggregation: flatten -> micro-CSR -> reg gather (bf16 input) -----
// L1=true : outb[i] = bf16( (1/max(deg,1)) * sum bf2f(xb[j]) )
// L1=false: outf[i] = (1/max(deg,1)) * sum bf2f(xb[j]) + hz[i] + bias
template<bool L1>
__global__ void __launch_bounds__(256) agg16_kernel(
        const int* __restrict__ bcnt, const int* __restrict__ tmp,
        const unsigned short* __restrict__ xb,
        const float* __restrict__ hz, const float* __restrict__ bias,
        unsigned short* __restrict__ outb, float* __restrict__ outf) {
    __shared__ int cgs[NG];
    __shared__ int goff[NG];
    __shared__ int total;
    __shared__ int scnt[16];
    __shared__ int soff[16];
    __shared__ int scur[16];
    __shared__ int plist[NG * CAPG];
    __shared__ int slist[NG * CAPG];

    const int b    = blockIdx.x;
    const int tid  = threadIdx.x;
    const int lane = tid & 63;
    const int wv   = tid >> 6;

    if (tid < NG) cgs[tid] = min(bcnt[tid * BSTR + b], CAPG);
    if (tid < 16) scnt[tid] = 0;
    __syncthreads();

    if (tid == 0) {
        int acc = 0;
#pragma unroll
        for (int g = 0; g < NG; ++g) { int c = cgs[g]; goff[g] = acc; acc += c; }
        total = acc;
    }
    __syncthreads();

    for (int t = tid; t < NG * CAPG; t += 256) {
        int g = t >> 7;
        int i = t & (CAPG - 1);
        if (i < cgs[g])
            plist[goff[g] + i] = tmp[((size_t)g * NBUK + b) * CAPG + i];
    }
    __syncthreads();

    const int cnt = total;
    for (int i = tid; i < cnt; i += 256)
        atomicAdd(&scnt[plist[i] >> 17], 1);
    __syncthreads();

    if (tid == 0) {
        int acc = 0;
#pragma unroll
        for (int r = 0; r < 16; ++r) {
            soff[r] = acc;
            scur[r] = acc;
            acc += scnt[r];
        }
    }
    __syncthreads();

    for (int i = tid; i < cnt; i += 256) {
        int p = plist[i];
        int pos = atomicAdd(&scur[p >> 17], 1);
        slist[pos] = p & 0x1FFFF;
    }
    __syncthreads();

#define LDX(c) bf2f(xb[(size_t)(c) * 64 + lane])
    for (int r = wv; r < 16; r += 4) {
        const int node = b * 16 + r;
        const int s = soff[r];
        const int d = scnt[r];
        float acc = 0.f;
        int j = 0;
        for (; j + 8 <= d; j += 8) {
            int c0 = slist[s + j + 0], c1 = slist[s + j + 1];
            int c2 = slist[s + j + 2], c3 = slist[s + j + 3];
            int c4 = slist[s + j + 4], c5 = slist[s + j + 5];
            int c6 = slist[s + j + 6], c7 = slist[s + j + 7];
            float v0 = LDX(c0), v1 = LDX(c1), v2 = LDX(c2), v3 = LDX(c3);
            float v4 = LDX(c4), v5 = LDX(c5), v6 = LDX(c6), v7 = LDX(c7);
            acc += ((v0 + v1) + (v2 + v3)) + ((v4 + v5) + (v6 + v7));
        }
        if (j + 4 <= d) {
            int c0 = slist[s + j + 0], c1 = slist[s + j + 1];
            int c2 = slist[s + j + 2], c3 = slist[s + j + 3];
            float v0 = LDX(c0), v1 = LDX(c1), v2 = LDX(c2), v3 = LDX(c3);
            acc += (v0 + v1) + (v2 + v3);
            j += 4;
        }
        for (; j < d; ++j) acc += LDX(slist[s + j]);

        const float inv = 1.0f / fmaxf((float)d, 1.0f);
        if (L1) {
            outb[(size_t)node * 64 + lane] = f2bf(acc * inv);
        } else {
            outf[(size_t)node * 64 + lane] =
                acc * inv + hz[(size_t)node * 64 + lane] + bias[lane];
        }
    }
#undef LDX
}

// ---------------- MFMA fused 2-layer GEMM: 128 nodes/block, 4 waves, 0 barriers ------
// GEMM1: h = relu(cat(aggb,embb) @ w1cat^T + b1)  (bf16 A from global, h -> LDS bf16)
// GEMM2: p2b = bf16(h @ w2l^T), hz = h @ w2r^T    (A from LDS, B = w2cat)
// Fragment layouts (mfma_f32_16x16x32_bf16): A: lane holds A[l&15][8*(l>>4)+j];
// B: lane holds B[8*(l>>4)+j][l&15]; C/D: col=lane&15, row=(lane>>4)*4+reg [m89/m91].
__global__ void __launch_bounds__(256) gemm_mfma_kernel(
        const unsigned short* __restrict__ aggb, const unsigned short* __restrict__ embb,
        const unsigned short* __restrict__ w1cat, const float* __restrict__ b1,
        const unsigned short* __restrict__ w2cat,
        unsigned short* __restrict__ p2b, float* __restrict__ hz) {
    __shared__ unsigned short h_lds[128 * 136];   // pad 136 -> conflict-free, 16B-aligned rows

    const int tid  = threadIdx.x;
    const int lane = tid & 63;
    const int w    = tid >> 6;          // wave 0..3, owns rows [w*32, w*32+32)
    const int l15  = lane & 15;
    const int lk   = lane >> 4;         // k-chunk 0..3
    const int n_base = blockIdx.x * 128;
    const int mrow0  = w * 32;

    f32x4 acc[2][8];
#pragma unroll
    for (int mt = 0; mt < 2; ++mt)
#pragma unroll
        for (int nt = 0; nt < 8; ++nt) acc[mt][nt] = (f32x4)(0.f);

    // ================= GEMM 1 =================
#pragma unroll
    for (int ks = 0; ks < 4; ++ks) {
        const int kc = ks * 32 + lk * 8;    // 0..120
        s16x8 a[2];
#pragma unroll
        for (int mt = 0; mt < 2; ++mt) {
            int n = n_base + mrow0 + mt * 16 + l15;
            s16x8 av = (s16x8)(short)0;
            if (n < NN) {
                const unsigned short* ap = (kc < 64)
                    ? (aggb + (size_t)n * 64 + kc)
                    : (embb + (size_t)n * 64 + (kc - 64));
                av = *(const s16x8*)ap;
            }
            a[mt] = av;
        }
#pragma unroll
        for (int nt = 0; nt < 8; ++nt) {
            s16x8 bv = *(const s16x8*)(w1cat + (nt * 16 + l15) * 128 + kc);
            acc[0][nt] = __builtin_amdgcn_mfma_f32_16x16x32_bf16(a[0], bv, acc[0][nt], 0, 0, 0);
            acc[1][nt] = __builtin_amdgcn_mfma_f32_16x16x32_bf16(a[1], bv, acc[1][nt], 0, 0, 0);
        }
    }

    // epilogue 1: bias + relu -> h_lds (wave-private rows; no barrier needed)
    float b1v[8];
#pragma unroll
    for (int nt = 0; nt < 8; ++nt) b1v[nt] = b1[nt * 16 + l15];
#pragma unroll
    for (int mt = 0; mt < 2; ++mt)
#pragma unroll
        for (int nt = 0; nt < 8; ++nt) {
            f32x4 d = acc[mt][nt];
            int o = nt * 16 + l15;
            int r0 = mrow0 + mt * 16 + lk * 4;
#pragma unroll
            for (int j = 0; j < 4; ++j)
                h_lds[(r0 + j) * 136 + o] = f2bf(fmaxf(d[j] + b1v[nt], 0.f));
        }

#pragma unroll
    for (int mt = 0; mt < 2; ++mt)
#pragma unroll
        for (int nt = 0; nt < 8; ++nt) acc[mt][nt] = (f32x4)(0.f);

    // ================= GEMM 2 =================
#pragma unroll
    for (int ks = 0; ks < 4; ++ks) {
        const int kc = ks * 32 + lk * 8;
        s16x8 a[2];
#pragma unroll
        for (int mt = 0; mt < 2; ++mt)
            a[mt] = *(const s16x8*)&h_lds[(mrow0 + mt * 16 + l15) * 136 + kc];
#pragma unroll
        for (int nt = 0; nt < 8; ++nt) {
            s16x8 bv = *(const s16x8*)(w2cat + (nt * 16 + l15) * 128 + kc);
            acc[0][nt] = __builtin_amdgcn_mfma_f32_16x16x32_bf16(a[0], bv, acc[0][nt], 0, 0, 0);
            acc[1][nt] = __builtin_amdgcn_mfma_f32_16x16x32_bf16(a[1], bv, acc[1][nt], 0, 0, 0);
        }
    }

    // epilogue 2: nt<4 -> p2b (bf16), nt>=4 -> hz (fp32)
#pragma unroll
    for (int mt = 0; mt < 2; ++mt)
#pragma unroll
        for (int nt = 0; nt < 8; ++nt) {
            f32x4 d = acc[mt][nt];
            int o = nt * 16 + l15;
            int r0 = n_base + mrow0 + mt * 16 + lk * 4;
#pragma unroll
            for (int j = 0; j < 4; ++j) {
                int r = r0 + j;
                if (r >= NN) continue;
                if (nt < 4) p2b[(size_t)r * 64 + o] = f2bf(d[j]);
                else        hz[(size_t)r * 64 + (o - 64)] = d[j];
            }
        }
}

// ---------------- decode: out[k] = dot(z[a[k]], z[b[k]]) ----------------
__global__ void decode_kernel(const int* __restrict__ a, const int* __restrict__ b,
                              const float* __restrict__ z, float* __restrict__ out) {
    int t = blockIdx.x * blockDim.x + threadIdx.x;
    int k = t >> 4;
    int q = t & 15;
    if (k >= NL) return;
    int ia = a[k], ib = b[k];
    float4 va = ((const float4*)z)[ia * 16 + q];
    float4 vb = ((const float4*)z)[ib * 16 + q];
    float s = va.x * vb.x + va.y * vb.y + va.z * vb.z + va.w * vb.w;
    s += __shfl_xor(s, 1, 64);
    s += __shfl_xor(s, 2, 64);
    s += __shfl_xor(s, 4, 64);
    s += __shfl_xor(s, 8, 64);
    if (q == 0) out[k] = s;
}

extern "C" void kernel_launch(void* const* d_in, const int* in_sizes, int n_in,
                              void* d_out, int out_size, void* d_ws, size_t ws_size,
                              hipStream_t stream) {
    const float* emb = (const float*)d_in[0];
    const float* w1l = (const float*)d_in[1];
    const float* w1r = (const float*)d_in[2];
    const float* b1  = (const float*)d_in[3];
    const float* w2l = (const float*)d_in[4];
    const float* w2r = (const float*)d_in[5];
    const float* b2  = (const float*)d_in[6];
    const int*   ei  = (const int*)d_in[7];
    const int*   eli = (const int*)d_in[8];
    float* out = (float*)d_out;

    // workspace layout (~116 MB)
    int* bcnt = (int*)d_ws;                                   // NG*BSTR = 50,176 ints
    int* tmp  = bcnt + NG * BSTR;                             // NG*NBUK*CAPG = 6,400,000 ints
    unsigned short* aggb  = (unsigned short*)(tmp + (size_t)NG * NBUK * CAPG);  // NN*64 bf16
    unsigned short* embb  = aggb + (size_t)NN * 64;           // NN*64 bf16
    unsigned short* p2b   = embb + (size_t)NN * 64;           // NN*64 bf16
    unsigned short* w1cat = p2b + (size_t)NN * 64;            // 128*128 bf16
    unsigned short* w2cat = w1cat + 128 * 128;                // 128*128 bf16
    float* hz = (float*)(w2cat + 128 * 128);                  // NN*64 f32
    float* z  = hz + (size_t)NN * 64;                         // NN*64 f32

    const int* src = ei;
    const int* dst = ei + NE;

    hipMemsetAsync(bcnt, 0, (size_t)NG * BSTR * sizeof(int), stream);

    bucket16_kernel<<<(NE / 4 + 255) / 256, 256, 0, stream>>>(src, dst, bcnt, tmp);
    conv_emb_kernel<<<(NN * 16 + 255) / 256, 256, 0, stream>>>(emb, embb);
    conv_w_kernel<<<64, 256, 0, stream>>>(w1l, w1r, w2l, w2r, w1cat, w2cat);

    // layer 1 aggregation (bf16 gather): aggb = bf16(mean-gather(embb))
    agg16_kernel<true><<<NBUK, 256, 0, stream>>>(bcnt, tmp, embb, nullptr, nullptr,
                                                 aggb, nullptr);

    // fused MFMA layers: h = relu(cat(agg,emb)@w1cat^T + b1); {p2b, hz} = h@{w2l,w2r}^T
    const int NT = (NN + 127) / 128;  // 782
    gemm_mfma_kernel<<<NT, 256, 0, stream>>>(aggb, embb, w1cat, b1, w2cat, p2b, hz);

    // layer 2 aggregation + fuse: z = mean-gather(p2b) + hz + b2
    agg16_kernel<false><<<NBUK, 256, 0, stream>>>(bcnt, tmp, p2b, hz, b2,
                                                  nullptr, z);

    // decode
    decode_kernel<<<(NL * 16 + 255) / 256, 256, 0, stream>>>(eli, eli + NL, z, out);
}

// Round 16
// 233.758 us; speedup vs baseline: 1.5110x; 1.0148x over previous
//
#include <hip/hip_runtime.h>

#define NN   100000
#define EMB  64
#define HID  128
#define OUTD 64
#define NE   1600000
#define NL   200000
#define NBUK 6250     // NN/16 buckets of exactly 16 nodes
#define NG   8        // per-XCD privatized copies
#define CAPG 128      // per-XCD bucket capacity (pow2); E=32
#define BSTR 6272     // padded per-group bcnt stride

#define BUK_BLOCKS  1563   // ceil(NE/4 / 256)
#define CEMB_BLOCKS 400    // grid-stride over NN*16 float4s
#define CW_BLOCKS   64     // 128*128 elems

typedef __attribute__((ext_vector_type(4))) float f32x4;
typedef __attribute__((ext_vector_type(8))) short s16x8;
typedef __attribute__((ext_vector_type(4))) unsigned short us4;
typedef __attribute__((ext_vector_type(4))) int v4i;

__device__ __forceinline__ unsigned short f2bf(float f) {
    unsigned u = __float_as_uint(f);
    u += 0x7FFFu + ((u >> 16) & 1u);   // RNE
    return (unsigned short)(u >> 16);
}
__device__ __forceinline__ float bf2f(unsigned short h) {
    return __uint_as_float(((unsigned)h) << 16);
}

__device__ __forceinline__ unsigned xcc_id() {
    unsigned v;
    asm volatile("s_getreg_b32 %0, hwreg(HW_REG_XCC_ID)" : "=s"(v));
    return v & (NG - 1);
}

// ---- merged prep: [0,1563) bucket edges (NT loads); [1563,1963) emb->bf16; rest w-cat ----
__global__ void __launch_bounds__(256) prep_kernel(
        const int* __restrict__ src, const int* __restrict__ dst,
        int* __restrict__ bcnt, int* __restrict__ tmp,
        const float* __restrict__ emb, unsigned short* __restrict__ embb,
        const float* __restrict__ w1l, const float* __restrict__ w1r,
        const float* __restrict__ w2l, const float* __restrict__ w2r,
        unsigned short* __restrict__ w1cat, unsigned short* __restrict__ w2cat) {
    const int bid = blockIdx.x;
    const int tid = threadIdx.x;

    if (bid < BUK_BLOCKS) {
        // ---- bucketing: 4 edges/thread, non-temporal edge reads (keep tmp L2-resident) ----
        int i = bid * 256 + tid;
        if (i >= NE / 4) return;
        unsigned g = xcc_id();
        int* cb = bcnt + g * BSTR;
        v4i d4 = __builtin_nontemporal_load((const v4i*)dst + i);
        v4i s4 = __builtin_nontemporal_load((const v4i*)src + i);
        int b0 = d4[0] >> 4, b1 = d4[1] >> 4, b2 = d4[2] >> 4, b3 = d4[3] >> 4;
        int p0 = atomicAdd(&cb[b0], 1);
        int p1 = atomicAdd(&cb[b1], 1);
        int p2 = atomicAdd(&cb[b2], 1);
        int p3 = atomicAdd(&cb[b3], 1);
        if (p0 < CAPG) tmp[((size_t)g * NBUK + b0) * CAPG + p0] = ((d4[0] & 15) << 17) | s4[0];
        if (p1 < CAPG) tmp[((size_t)g * NBUK + b1) * CAPG + p1] = ((d4[1] & 15) << 17) | s4[1];
        if (p2 < CAPG) tmp[((size_t)g * NBUK + b2) * CAPG + p2] = ((d4[2] & 15) << 17) | s4[2];
        if (p3 < CAPG) tmp[((size_t)g * NBUK + b3) * CAPG + p3] = ((d4[3] & 15) << 17) | s4[3];
    } else if (bid < BUK_BLOCKS + CEMB_BLOCKS) {
        // ---- emb fp32 -> bf16, grid-stride ----
        for (int i = (bid - BUK_BLOCKS) * 256 + tid; i < NN * 16; i += CEMB_BLOCKS * 256) {
            float4 v = ((const float4*)emb)[i];
            us4 o;
            o.x = f2bf(v.x); o.y = f2bf(v.y); o.z = f2bf(v.z); o.w = f2bf(v.w);
            ((us4*)embb)[i] = o;
        }
    } else {
        // ---- weight concat -> bf16 ----
        int t = (bid - BUK_BLOCKS - CEMB_BLOCKS) * 256 + tid;
        if (t >= 128 * 128) return;
        int o = t >> 7, k = t & 127;
        w1cat[t] = f2bf(k < 64 ? w1l[o * 64 + k] : w1r[o * 64 + (k - 64)]);
        w2cat[t] = f2bf(o < 64 ? w2l[o * 128 + k] : w2r[(o - 64) * 128 + k]);
    }
}

// ------- per-bucket aggregation: flatten -> micro-CSR -> reg gather (bf16 input) -----
// L1=true : outb[i] = bf16( (1/max(deg,1)) * sum bf2f(xb[j]) )
// L1=false: outz[i] = bf16( (1/max(deg,1)) * sum bf2f(xb[j]) + hz[i] + bias )
template<bool L1>
__global__ void __launch_bounds__(256) agg16_kernel(
        const int* __restrict__ bcnt, const int* __restrict__ tmp,
        const unsigned short* __restrict__ xb,
        const float* __restrict__ hz, const float* __restrict__ bias,
        unsigned short* __restrict__ outb) {
    __shared__ int cgs[NG];
    __shared__ int goff[NG];
    __shared__ int total;
    __shared__ int scnt[16];
    __shared__ int soff[16];
    __shared__ int scur[16];
    __shared__ int plist[NG * CAPG];
    __shared__ int slist[NG * CAPG];

    const int b    = blockIdx.x;
    const int tid  = threadIdx.x;
    const int lane = tid & 63;
    const int wv   = tid >> 6;

    if (tid < NG) cgs[tid] = min(bcnt[tid * BSTR + b], CAPG);
    if (tid < 16) scnt[tid] = 0;
    __syncthreads();

    if (tid == 0) {
        int acc = 0;
#pragma unroll
        for (int g = 0; g < NG; ++g) { int c = cgs[g]; goff[g] = acc; acc += c; }
        total = acc;
    }
    __syncthreads();

    for (int t = tid; t < NG * CAPG; t += 256) {
        int g = t >> 7;
        int i = t & (CAPG - 1);
        if (i < cgs[g])
            plist[goff[g] + i] = __builtin_nontemporal_load(
                tmp + ((size_t)g * NBUK + b) * CAPG + i);
    }
    __syncthreads();

    const int cnt = total;
    for (int i = tid; i < cnt; i += 256)
        atomicAdd(&scnt[plist[i] >> 17], 1);
    __syncthreads();

    if (tid == 0) {
        int acc = 0;
#pragma unroll
        for (int r = 0; r < 16; ++r) {
            soff[r] = acc;
            scur[r] = acc;
            acc += scnt[r];
        }
    }
    __syncthreads();

    for (int i = tid; i < cnt; i += 256) {
        int p = plist[i];
        int pos = atomicAdd(&scur[p >> 17], 1);
        slist[pos] = p & 0x1FFFF;
    }
    __syncthreads();

#define LDX(c) bf2f(xb[(size_t)(c) * 64 + lane])
    for (int r = wv; r < 16; r += 4) {
        const int node = b * 16 + r;
        const int s = soff[r];
        const int d = scnt[r];
        float acc = 0.f;
        int j = 0;
        for (; j + 8 <= d; j += 8) {
            int c0 = slist[s + j + 0], c1 = slist[s + j + 1];
            int c2 = slist[s + j + 2], c3 = slist[s + j + 3];
            int c4 = slist[s + j + 4], c5 = slist[s + j + 5];
            int c6 = slist[s + j + 6], c7 = slist[s + j + 7];
            float v0 = LDX(c0), v1 = LDX(c1), v2 = LDX(c2), v3 = LDX(c3);
            float v4 = LDX(c4), v5 = LDX(c5), v6 = LDX(c6), v7 = LDX(c7);
            acc += ((v0 + v1) + (v2 + v3)) + ((v4 + v5) + (v6 + v7));
        }
        if (j + 4 <= d) {
            int c0 = slist[s + j + 0], c1 = slist[s + j + 1];
            int c2 = slist[s + j + 2], c3 = slist[s + j + 3];
            float v0 = LDX(c0), v1 = LDX(c1), v2 = LDX(c2), v3 = LDX(c3);
            acc += (v0 + v1) + (v2 + v3);
            j += 4;
        }
        for (; j < d; ++j) acc += LDX(slist[s + j]);

        const float inv = 1.0f / fmaxf((float)d, 1.0f);
        if (L1) {
            outb[(size_t)node * 64 + lane] = f2bf(acc * inv);
        } else {
            outb[(size_t)node * 64 + lane] =
                f2bf(acc * inv + hz[(size_t)node * 64 + lane] + bias[lane]);
        }
    }
#undef LDX
}

// ---------------- MFMA fused 2-layer GEMM: 128 nodes/block, 4 waves, 0 barriers ------
// GEMM1: h = relu(cat(aggb,embb) @ w1cat^T + b1)  (bf16 A from global, h -> LDS bf16)
// GEMM2: p2b = bf16(h @ w2l^T), hz = h @ w2r^T    (A from LDS, B = w2cat)
// Fragment layouts (mfma_f32_16x16x32_bf16): A: lane holds A[l&15][8*(l>>4)+j];
// B: lane holds B[8*(l>>4)+j][l&15]; C/D: col=lane&15, row=(lane>>4)*4+reg [m89/m91].
__global__ void __launch_bounds__(256) gemm_mfma_kernel(
        const unsigned short* __restrict__ aggb, const unsigned short* __restrict__ embb,
        const unsigned short* __restrict__ w1cat, const float* __restrict__ b1,
        const unsigned short* __restrict__ w2cat,
        unsigned short* __restrict__ p2b, float* __restrict__ hz) {
    __shared__ unsigned short h_lds[128 * 136];   // pad 136 -> conflict-free, 16B-aligned rows

    const int tid  = threadIdx.x;
    const int lane = tid & 63;
    const int w    = tid >> 6;          // wave 0..3, owns rows [w*32, w*32+32)
    const int l15  = lane & 15;
    const int lk   = lane >> 4;         // k-chunk 0..3
    const int n_base = blockIdx.x * 128;
    const int mrow0  = w * 32;

    f32x4 acc[2][8];
#pragma unroll
    for (int mt = 0; mt < 2; ++mt)
#pragma unroll
        for (int nt = 0; nt < 8; ++nt) acc[mt][nt] = (f32x4)(0.f);

    // ================= GEMM 1 =================
#pragma unroll
    for (int ks = 0; ks < 4; ++ks) {
        const int kc = ks * 32 + lk * 8;    // 0..120
        s16x8 a[2];
#pragma unroll
        for (int mt = 0; mt < 2; ++mt) {
            int n = n_base + mrow0 + mt * 16 + l15;
            s16x8 av = (s16x8)(short)0;
            if (n < NN) {
                const unsigned short* ap = (kc < 64)
                    ? (aggb + (size_t)n * 64 + kc)
                    : (embb + (size_t)n * 64 + (kc - 64));
                av = *(const s16x8*)ap;
            }
            a[mt] = av;
        }
#pragma unroll
        for (int nt = 0; nt < 8; ++nt) {
            s16x8 bv = *(const s16x8*)(w1cat + (nt * 16 + l15) * 128 + kc);
            acc[0][nt] = __builtin_amdgcn_mfma_f32_16x16x32_bf16(a[0], bv, acc[0][nt], 0, 0, 0);
            acc[1][nt] = __builtin_amdgcn_mfma_f32_16x16x32_bf16(a[1], bv, acc[1][nt], 0, 0, 0);
        }
    }

    // epilogue 1: bias + relu -> h_lds (wave-private rows; no barrier needed)
    float b1v[8];
#pragma unroll
    for (int nt = 0; nt < 8; ++nt) b1v[nt] = b1[nt * 16 + l15];
#pragma unroll
    for (int mt = 0; mt < 2; ++mt)
#pragma unroll
        for (int nt = 0; nt < 8; ++nt) {
            f32x4 d = acc[mt][nt];
            int o = nt * 16 + l15;
            int r0 = mrow0 + mt * 16 + lk * 4;
#pragma unroll
            for (int j = 0; j < 4; ++j)
                h_lds[(r0 + j) * 136 + o] = f2bf(fmaxf(d[j] + b1v[nt], 0.f));
        }

#pragma unroll
    for (int mt = 0; mt < 2; ++mt)
#pragma unroll
        for (int nt = 0; nt < 8; ++nt) acc[mt][nt] = (f32x4)(0.f);

    // ================= GEMM 2 =================
#pragma unroll
    for (int ks = 0; ks < 4; ++ks) {
        const int kc = ks * 32 + lk * 8;
        s16x8 a[2];
#pragma unroll
        for (int mt = 0; mt < 2; ++mt)
            a[mt] = *(const s16x8*)&h_lds[(mrow0 + mt * 16 + l15) * 136 + kc];
#pragma unroll
        for (int nt = 0; nt < 8; ++nt) {
            s16x8 bv = *(const s16x8*)(w2cat + (nt * 16 + l15) * 128 + kc);
            acc[0][nt] = __builtin_amdgcn_mfma_f32_16x16x32_bf16(a[0], bv, acc[0][nt], 0, 0, 0);
            acc[1][nt] = __builtin_amdgcn_mfma_f32_16x16x32_bf16(a[1], bv, acc[1][nt], 0, 0, 0);
        }
    }

    // epilogue 2: nt<4 -> p2b (bf16), nt>=4 -> hz (fp32)
#pragma unroll
    for (int mt = 0; mt < 2; ++mt)
#pragma unroll
        for (int nt = 0; nt < 8; ++nt) {
            f32x4 d = acc[mt][nt];
            int o = nt * 16 + l15;
            int r0 = n_base + mrow0 + mt * 16 + lk * 4;
#pragma unroll
            for (int j = 0; j < 4; ++j) {
                int r = r0 + j;
                if (r >= NN) continue;
                if (nt < 4) p2b[(size_t)r * 64 + o] = f2bf(d[j]);
                else        hz[(size_t)r * 64 + (o - 64)] = d[j];
            }
        }
}

// ---------------- decode (bf16 z): out[k] = dot(z[a[k]], z[b[k]]) ----------------
__global__ void decode_kernel(const int* __restrict__ a, const int* __restrict__ b,
                              const unsigned short* __restrict__ zb, float* __restrict__ out) {
    int t = blockIdx.x * blockDim.x + threadIdx.x;
    int k = t >> 4;
    int q = t & 15;
    if (k >= NL) return;
    int ia = a[k], ib = b[k];
    us4 va = ((const us4*)zb)[ia * 16 + q];
    us4 vb = ((const us4*)zb)[ib * 16 + q];
    float s = bf2f(va.x) * bf2f(vb.x) + bf2f(va.y) * bf2f(vb.y)
            + bf2f(va.z) * bf2f(vb.z) + bf2f(va.w) * bf2f(vb.w);
    s += __shfl_xor(s, 1, 64);
    s += __shfl_xor(s, 2, 64);
    s += __shfl_xor(s, 4, 64);
    s += __shfl_xor(s, 8, 64);
    if (q == 0) out[k] = s;
}

extern "C" void kernel_launch(void* const* d_in, const int* in_sizes, int n_in,
                              void* d_out, int out_size, void* d_ws, size_t ws_size,
                              hipStream_t stream) {
    const float* emb = (const float*)d_in[0];
    const float* w1l = (const float*)d_in[1];
    const float* w1r = (const float*)d_in[2];
    const float* b1  = (const float*)d_in[3];
    const float* w2l = (const float*)d_in[4];
    const float* w2r = (const float*)d_in[5];
    const float* b2  = (const float*)d_in[6];
    const int*   ei  = (const int*)d_in[7];
    const int*   eli = (const int*)d_in[8];
    float* out = (float*)d_out;

    // workspace layout (~103 MB)
    int* bcnt = (int*)d_ws;                                   // NG*BSTR = 50,176 ints
    int* tmp  = bcnt + NG * BSTR;                             // NG*NBUK*CAPG = 6,400,000 ints
    unsigned short* aggb  = (unsigned short*)(tmp + (size_t)NG * NBUK * CAPG);  // NN*64 bf16
    unsigned short* embb  = aggb + (size_t)NN * 64;           // NN*64 bf16
    unsigned short* p2b   = embb + (size_t)NN * 64;           // NN*64 bf16
    unsigned short* zb    = p2b + (size_t)NN * 64;            // NN*64 bf16
    unsigned short* w1cat = zb + (size_t)NN * 64;             // 128*128 bf16
    unsigned short* w2cat = w1cat + 128 * 128;                // 128*128 bf16
    float* hz = (float*)(w2cat + 128 * 128);                  // NN*64 f32

    const int* src = ei;
    const int* dst = ei + NE;

    hipMemsetAsync(bcnt, 0, (size_t)NG * BSTR * sizeof(int), stream);

    // merged prep: bucket edges (NT loads) + emb->bf16 + weight concat, one dispatch
    prep_kernel<<<BUK_BLOCKS + CEMB_BLOCKS + CW_BLOCKS, 256, 0, stream>>>(
        src, dst, bcnt, tmp, emb, embb, w1l, w1r, w2l, w2r, w1cat, w2cat);

    // layer 1 aggregation (bf16 gather): aggb = bf16(mean-gather(embb))
    agg16_kernel<true><<<NBUK, 256, 0, stream>>>(bcnt, tmp, embb, nullptr, nullptr, aggb);

    // fused MFMA layers: h = relu(cat(agg,emb)@w1cat^T + b1); {p2b, hz} = h@{w2l,w2r}^T
    const int NT = (NN + 127) / 128;  // 782
    gemm_mfma_kernel<<<NT, 256, 0, stream>>>(aggb, embb, w1cat, b1, w2cat, p2b, hz);

    // layer 2 aggregation + fuse: zb = bf16(mean-gather(p2b) + hz + b2)
    agg16_kernel<false><<<NBUK, 256, 0, stream>>>(bcnt, tmp, p2b, hz, b2, zb);

    // decode
    decode_kernel<<<(NL * 16 + 255) / 256, 256, 0, stream>>>(eli, eli + NL, zb, out);
}